// Round 3
// baseline (829.120 us; speedup 1.0000x reference)
//
#include <hip/hip_runtime.h>
#include <cmath>

#define NS 51
#define ND 50
#define PLANE 1048576            // 1024*1024
#define DOG_ELEMS (ND * PLANE)   // 52428800
#define WPSTRIDE 144             // padded 1-D kernel: 16 zeros | taps | zeros

// ---------------- K0: extract normalized 1-D kernels + radii from 2-D weight ----
__global__ void dog_prep(const float* __restrict__ weight,
                         float* __restrict__ wp,
                         int* __restrict__ rarr, int S) {
    int i = blockIdx.x;
    int R = (S - 1) >> 1;
    const float* row = weight + ((size_t)i * S + R) * S;   // center row of scale i
    int t = threadIdx.x;
    for (int j = t; j < WPSTRIDE; j += blockDim.x) wp[i * WPSTRIDE + j] = 0.f;
    __syncthreads();
    if (t == 0) {
        float sum = 0.f;
        for (int j = 0; j < S; ++j) sum += row[j];
        int pad = 0;
        while (pad < R && row[pad] == 0.f) ++pad;
        int r = R - pad;
        rarr[i] = r;
        for (int j = 0; j <= 2 * r; ++j)
            wp[i * WPSTRIDE + 16 + j] = row[pad + j] / sum;
    }
}

// ---------------- K1: horizontal blur -------------------------------------------
// 2 rows/block (2 groups x 128 threads), 8 outputs/thread. LDS row 8-way
// interleaved (stride 143, odd) so stride-8 reads are conflict-free. Staging
// loads are float4 (input row window is 4-aligned at both clip boundaries).
__global__ __launch_bounds__(256) void dog_hblur(
        const float* __restrict__ in, float* __restrict__ tmpH,
        const float* __restrict__ wp, const int* __restrict__ rarr) {
    int i = blockIdx.y;
    int t = threadIdx.x;
    int grp = t >> 7;
    int tl = t & 127;
    int y = (blockIdx.x << 1) | grp;
    int r = rarr[i];
    const float* __restrict__ w = wp + i * WPSTRIDE;
    __shared__ float srow[2][1144];                 // 8 phases x 143
    const float* inrow = in + ((size_t)y << 10);
    for (int e = tl; e < 286; e += 128) {           // 286 float4 = x in [-56,1088)
        int x = (e << 2) - 56;
        float4 v = make_float4(0.f, 0.f, 0.f, 0.f);
        if (x >= 0 && x < 1024) v = *(const float4*)(inrow + x);
        float vv[4] = {v.x, v.y, v.z, v.w};
        int j = e << 2;                             // = x + 56
#pragma unroll
        for (int c = 0; c < 4; ++c) {
            int jj = j + c;
            srow[grp][(jj & 7) * 143 + (jj >> 3)] = vv[c];
        }
    }
    __syncthreads();
    float acc[8];
#pragma unroll
    for (int k = 0; k < 8; ++k) acc[k] = 0.f;
    int c0 = 56 - r;                                // >= 5
    int mcount = ((2 * r + 15) >> 3) << 3;          // >= 2r+8
    const float* s = srow[grp];
    for (int m = 0; m < mcount; m += 8) {
        float v[8];
#pragma unroll
        for (int j2 = 0; j2 < 8; ++j2) {
            int q = m + j2 + c0;                    // uniform
            v[j2] = s[(q & 7) * 143 + tl + (q >> 3)];
        }
#pragma unroll
        for (int j2 = 0; j2 < 8; ++j2)
#pragma unroll
            for (int k = 0; k < 8; ++k)
                acc[k] = fmaf(w[16 + m + j2 - k], v[j2], acc[k]);
    }
    float* o = tmpH + (((size_t)i) << 20) + ((size_t)y << 10) + (tl << 3);
    *(float4*)o       = make_float4(acc[0], acc[1], acc[2], acc[3]);
    *(float4*)(o + 4) = make_float4(acc[4], acc[5], acc[6], acc[7]);
}

// ---------------- K2: fused vertical blur + DoG + 3x3x3 pool + epilogue ---------
// 60x14 output tile/block. Per scale: stage tmpH (float4), vconv (4 rows/thread,
// 8-way m-unroll, static weight idx), DoG -> 2-ring (−inf outside image),
// 3x3 xy-max -> 3-ring, emit lm/sm for scale j=i-2. dog never hits HBM.
#define XO 60
#define YO 14
#define SS 68                    // stage & D-ring stride (17 float4)
#define MS 60                    // M-ring stride (15 float4)
#define NROWMAX 124

__device__ __forceinline__ void dog_emit(
        int j, bool hasNext, int t, int x0, int y0, float thr,
        const float (*Mr)[YO * MS], const float (*Dr)[16 * SS],
        float* __restrict__ out) {
    if (t >= 210) return;                           // 14 rows x 15 quads
    int ro = t / 15, q = t - ro * 15;
    int off = ro * MS + (q << 2);
    float4 p = *(const float4*)(Mr[j % 3] + off);
    if (hasNext) {
        float4 u = *(const float4*)(Mr[(j + 1) % 3] + off);
        p.x = fmaxf(p.x, u.x); p.y = fmaxf(p.y, u.y);
        p.z = fmaxf(p.z, u.z); p.w = fmaxf(p.w, u.w);
    }
    if (j >= 1) {
        float4 u = *(const float4*)(Mr[(j + 2) % 3] + off);
        p.x = fmaxf(p.x, u.x); p.y = fmaxf(p.y, u.y);
        p.z = fmaxf(p.z, u.z); p.w = fmaxf(p.w, u.w);
    }
    const float* D = Dr[j & 1] + (ro + 1) * SS + (q << 2);
    float4 d0 = *(const float4*)D;                  // D cols 4q..4q+3 (tx-space)
    float4 d1 = *(const float4*)(D + 4);            // 4q+4..4q+7
    // output col x0+4q+c  <->  tx = 4q+2+c
    float dvx = d0.z, dvy = d0.w, dvz = d1.x, dvw = d1.y;
    float4 lm, sm;
    lm.x = fmaxf(p.x + thr, 0.f); lm.y = fmaxf(p.y + thr, 0.f);
    lm.z = fmaxf(p.z + thr, 0.f); lm.w = fmaxf(p.w + thr, 0.f);
    sm.x = 1.f - lm.x + dvx + thr; sm.y = 1.f - lm.y + dvy + thr;
    sm.z = 1.f - lm.z + dvz + thr; sm.w = 1.f - lm.w + dvw + thr;
    int gy = y0 + ro, gx = x0 + (q << 2);
    if (gy < 1024 && gx < 1024) {
        size_t idx = (((size_t)j) << 20) + ((size_t)gy << 10) + gx;
        *(float4*)(out + idx) = lm;
        *(float4*)(out + DOG_ELEMS + idx) = sm;
    }
}

__global__ __launch_bounds__(256) void dog_fused(
        const float* __restrict__ tmpH, float* __restrict__ out,
        const float* __restrict__ wp, const int* __restrict__ rarr,
        const float* __restrict__ sigmas, const float* __restrict__ thr_p) {
    int x0 = blockIdx.x * XO;
    int y0 = blockIdx.y * YO;
    int t = threadIdx.x;
    int tx = t & 63, rg = t >> 6;                   // wave-uniform rg
    float thr = thr_p[0];
    const float NEG = -__builtin_huge_valf();

    __shared__ float stage[NROWMAX * SS];           // 33.0 KB
    __shared__ float Dr[2][16 * SS];                //  8.5 KB
    __shared__ float Mr[3][YO * MS];                //  9.8 KB  (total 51.3 KB)

    float gprev[4] = {0.f, 0.f, 0.f, 0.f};

    for (int i = 0; i < NS; ++i) {
        int r = rarr[i];
        int mcount = ((2 * r + 11) >> 3) << 3;      // >= 2r+4, mult of 8
        int nstage = mcount + 12;                   // <= 124 rows
        // A: stage tmpH rows y0-1-r .. , cols x0-4..x0+63 (17 float4)
        int nf4 = nstage * 17;
        for (int e = t; e < nf4; e += 256) {
            int row = e / 17, c = e - row * 17;
            int gy = y0 - 1 - r + row;
            int gx = x0 - 4 + (c << 2);
            float4 v = make_float4(0.f, 0.f, 0.f, 0.f);
            if ((unsigned)gy < 1024u && (unsigned)gx < 1024u)
                v = *(const float4*)(tmpH + (((size_t)i) << 20) + ((size_t)gy << 10) + gx);
            ((float4*)stage)[e] = v;
        }
        __syncthreads();
        // C: vertical conv, 4 rows/thread at col tx (tx-space col = x0-2+tx)
        const float* __restrict__ w = wp + i * WPSTRIDE;
        float acc[4] = {0.f, 0.f, 0.f, 0.f};
        int base = (rg << 2) * SS + tx + 2;
        for (int m = 0; m < mcount; m += 8) {
            float v[8];
#pragma unroll
            for (int j = 0; j < 8; ++j) v[j] = stage[base + (m + j) * SS];
#pragma unroll
            for (int j = 0; j < 8; ++j)
#pragma unroll
                for (int k = 0; k < 4; ++k)
                    acc[k] = fmaf(w[16 + m + j - k], v[j], acc[k]);
        }
        // D: DoG -> ring (−inf where outside image)
        if (i >= 1) {
            float sg = sigmas[i - 1];
            float* D = Dr[(i - 1) & 1];
            int xc = x0 - 2 + tx;
#pragma unroll
            for (int k = 0; k < 4; ++k) {
                int rl = (rg << 2) + k;
                int yr = y0 - 1 + rl;
                bool ok = ((unsigned)yr < 1024u) && ((unsigned)xc < 1024u);
                D[rl * SS + tx] = ok ? (gprev[k] - acc[k]) * sg : NEG;
            }
        }
#pragma unroll
        for (int k = 0; k < 4; ++k) gprev[k] = acc[k];
        __syncthreads();
        // F: 3x3 xy-max of D_{i-1} -> M ring
        if (i >= 1) {
            const float* D = Dr[(i - 1) & 1];
            float* M = Mr[(i - 1) % 3];
            if (t < 210) {
                int ro = t / 15, q = t - ro * 15;
                float4 mm = make_float4(NEG, NEG, NEG, NEG);
#pragma unroll
                for (int d = 0; d < 3; ++d) {
                    const float* p = D + (ro + d) * SS + (q << 2);
                    float4 a = *(const float4*)p;
                    float4 b = *(const float4*)(p + 4);
                    mm.x = fmaxf(mm.x, fmaxf(fmaxf(a.y, a.z), a.w));
                    mm.y = fmaxf(mm.y, fmaxf(fmaxf(a.z, a.w), b.x));
                    mm.z = fmaxf(mm.z, fmaxf(fmaxf(a.w, b.x), b.y));
                    mm.w = fmaxf(mm.w, fmaxf(fmaxf(b.x, b.y), b.z));
                }
                *(float4*)(M + ro * MS + (q << 2)) = mm;
            }
        }
        __syncthreads();
        // H: emit scale j = i-2
        if (i >= 2)
            dog_emit(i - 2, true, t, x0, y0, thr, Mr, Dr, out);
    }
    // tail: j = 49 (no M_50)
    dog_emit(ND - 1, false, t, x0, y0, thr, Mr, Dr, out);
}

extern "C" void kernel_launch(void* const* d_in, const int* in_sizes, int n_in,
                              void* d_out, int out_size, void* d_ws, size_t ws_size,
                              hipStream_t stream) {
    const float* input  = (const float*)d_in[0];
    const float* weight = (const float*)d_in[1];
    const float* sigmas = (const float*)d_in[2];
    const float* thr    = (const float*)d_in[3];
    float* out = (float*)d_out;

    int S = 103;
    if (n_in > 1 && in_sizes[1] >= NS) {
        int s2 = in_sizes[1] / NS;
        S = (int)(sqrt((double)s2) + 0.5);
    }

    size_t need = (size_t)NS * PLANE * 4 + (size_t)NS * WPSTRIDE * 4 + NS * 4 + 256;
    if (ws_size < need) return;   // insufficient scratch -> visible validation failure

    float* tmpH = (float*)d_ws;                    // 51 planes (214 MB)
    float* wp   = tmpH + (size_t)NS * PLANE;       // 51 * 144 floats
    int*   rarr = (int*)(wp + NS * WPSTRIDE);      // 51 ints

    dog_prep <<<NS, 128, 0, stream>>>(weight, wp, rarr, S);
    dog_hblur<<<dim3(512, NS), 256, 0, stream>>>(input, tmpH, wp, rarr);
    dog_fused<<<dim3(18, 74), 256, 0, stream>>>(tmpH, out, wp, rarr, sigmas, thr);
}

// Round 4
// 509.075 us; speedup vs baseline: 1.6287x; 1.6287x over previous
//
#include <hip/hip_runtime.h>
#include <cmath>

#define NS 51
#define ND 50
#define PLANE 1048576            // 1024*1024
#define DOG_ELEMS (ND * PLANE)   // 52428800
#define WPSTRIDE 144             // padded 1-D kernel: 17 zeros | taps | zeros

// ---------------- K0: extract normalized 1-D kernels + radii from 2-D weight ----
// taps stored at wp[i*144 + 17 + u], u in [0,2r]; zeros elsewhere.
// max index used by consumers: 17 + 2r + 24 <= 143 for r <= 51.
__global__ void dog_prep(const float* __restrict__ weight,
                         float* __restrict__ wp,
                         int* __restrict__ rarr, int S) {
    int i = blockIdx.x;
    int R = (S - 1) >> 1;
    const float* row = weight + ((size_t)i * S + R) * S;   // center row of scale i
    int t = threadIdx.x;
    for (int j = t; j < WPSTRIDE; j += blockDim.x) wp[i * WPSTRIDE + j] = 0.f;
    __syncthreads();
    if (t == 0) {
        float sum = 0.f;
        for (int j = 0; j < S; ++j) sum += row[j];
        int pad = 0;
        while (pad < R && row[pad] == 0.f) ++pad;
        int r = R - pad;
        rarr[i] = r;
        for (int j = 0; j <= 2 * r; ++j)
            wp[i * WPSTRIDE + 17 + j] = row[pad + j] / sum;
    }
}

// ---------------- K1: horizontal blur -------------------------------------------
// 2 rows/block (2 groups x 128 threads), 8 outputs/thread. LDS row 8-way
// interleaved (stride 143, odd) so stride-8 reads are conflict-free.
__global__ __launch_bounds__(256) void dog_hblur(
        const float* __restrict__ in, float* __restrict__ tmpH,
        const float* __restrict__ wp, const int* __restrict__ rarr) {
    int i = blockIdx.y;
    int t = threadIdx.x;
    int grp = t >> 7;
    int tl = t & 127;
    int y = (blockIdx.x << 1) | grp;
    int r = rarr[i];
    const float* __restrict__ w = wp + i * WPSTRIDE;
    __shared__ float srow[2][1144];                 // 8 phases x 143
    const float* inrow = in + ((size_t)y << 10);
    for (int e = tl; e < 286; e += 128) {           // 286 float4 = x in [-56,1088)
        int x = (e << 2) - 56;
        float4 v = make_float4(0.f, 0.f, 0.f, 0.f);
        if (x >= 0 && x < 1024) v = *(const float4*)(inrow + x);
        float vv[4] = {v.x, v.y, v.z, v.w};
        int j = e << 2;                             // = x + 56
#pragma unroll
        for (int c = 0; c < 4; ++c) {
            int jj = j + c;
            srow[grp][(jj & 7) * 143 + (jj >> 3)] = vv[c];
        }
    }
    __syncthreads();
    float acc[8];
#pragma unroll
    for (int k = 0; k < 8; ++k) acc[k] = 0.f;
    int c0 = 56 - r;
    int mcount = ((2 * r + 15) >> 3) << 3;          // >= 2r+8
    const float* s = srow[grp];
    for (int m = 0; m < mcount; m += 8) {
        float v[8];
#pragma unroll
        for (int j2 = 0; j2 < 8; ++j2) {
            int q = m + j2 + c0;                    // uniform
            v[j2] = s[(q & 7) * 143 + tl + (q >> 3)];
        }
#pragma unroll
        for (int j2 = 0; j2 < 8; ++j2)
#pragma unroll
            for (int k = 0; k < 8; ++k)
                acc[k] = fmaf(w[17 + m + j2 - k], v[j2], acc[k]);
    }
    float* o = tmpH + (((size_t)i) << 20) + ((size_t)y << 10) + (tl << 3);
    *(float4*)o       = make_float4(acc[0], acc[1], acc[2], acc[3]);
    *(float4*)(o + 4) = make_float4(acc[4], acc[5], acc[6], acc[7]);
}

// ---------------- K2: fused vconv + DoG + 3x3x3 pool + epilogue, LDS-free -------
// Wave = 64 lanes = 64 consecutive x (62 output x + 1 halo lane each side).
// Thread: 18 g-rows (16 out + y-halo) in registers for one column; loops a
// cost-balanced scale chunk. Pool: x via shfl, y in-register, scale via A/B
// running-max chain. No LDS, no barriers.
__global__ __launch_bounds__(256) void dog_fused(
        const float* __restrict__ tmpH, float* __restrict__ out,
        const float* __restrict__ wp, const int* __restrict__ rarr,
        const float* __restrict__ sigmas, const float* __restrict__ thr_p) {
    const int jlo_t[5] = {0, 20, 30, 38, 44};
    const int jhi_t[5] = {19, 29, 37, 43, 49};
    int t = threadIdx.x;
    int lane = t & 63;
    int wv = t >> 6;
    int ybg = blockIdx.x;                 // 0..15  (fastest: y-adjacent L2 reuse)
    int wx  = blockIdx.y;                 // 0..16
    int zc  = blockIdx.z;                 // 0..4
    int yg = (ybg << 2) | wv;             // 0..63
    int y0 = yg << 4;
    int x = wx * 62 - 1 + lane;           // -1 .. 1054
    int xi = min(max(x, 0), 1023);
    bool xok = ((unsigned)x < 1024u);
    float thr = thr_p[0];
    const float NEG = -__builtin_huge_valf();

    int jlo = jlo_t[zc], jhi = jhi_t[zc];
    int istart = jlo > 0 ? jlo - 1 : 0;
    int iend = (jhi + 2 < 50) ? jhi + 2 : 50;

    float gprev[18], A[16], B[16], Dprev[16];
#pragma unroll
    for (int k = 0; k < 18; ++k) gprev[k] = 0.f;
#pragma unroll
    for (int k = 0; k < 16; ++k) { A[k] = NEG; B[k] = NEG; Dprev[k] = 0.f; }

    for (int i = istart; i <= iend; ++i) {
        int r = rarr[i];
        const float* __restrict__ w = wp + i * WPSTRIDE;
        const float* __restrict__ plane = tmpH + ((size_t)i << 20);
        int mcount = ((2 * r + 25) >> 3) << 3;       // >= 2r+18
        int gy0 = y0 - 1 - r;
        float acc[18];
#pragma unroll
        for (int k = 0; k < 18; ++k) acc[k] = 0.f;
        for (int m = 0; m < mcount; m += 8) {
            float v[8];
#pragma unroll
            for (int j = 0; j < 8; ++j) {
                int gy = gy0 + m + j;
                int gyc = min(max(gy, 0), 1023);
                float lv = plane[((size_t)gyc << 10) + xi];
                v[j] = ((unsigned)gy < 1024u) ? lv : 0.f;
            }
#pragma unroll
            for (int j = 0; j < 8; ++j)
#pragma unroll
                for (int k = 0; k < 18; ++k)
                    acc[k] = fmaf(w[17 + m + j - k], v[j], acc[k]);
        }
        if (i > istart) {
            int d = i - 1;
            float sg = sigmas[d];
            // DoG in place of gprev; -inf outside image (pool pad semantics)
#pragma unroll
            for (int k = 0; k < 18; ++k) {
                int gy = y0 - 1 + k;
                bool ok = xok && ((unsigned)gy < 1024u);
                gprev[k] = ok ? (gprev[k] - acc[k]) * sg : NEG;
            }
            float xm[18];
#pragma unroll
            for (int k = 0; k < 18; ++k) {
                float c = gprev[k];
                float l = __shfl_up(c, 1);
                float rr = __shfl_down(c, 1);
                xm[k] = fmaxf(fmaxf(l, rr), c);
            }
            float ym[16];
#pragma unroll
            for (int k = 0; k < 16; ++k)
                ym[k] = fmaxf(fmaxf(xm[k], xm[k + 1]), xm[k + 2]);
            if (d - 1 >= jlo) {                      // emit j = d-1
                bool st = xok && lane >= 1 && lane <= 62;
                size_t ob = ((size_t)(d - 1) << 20) + ((size_t)y0 << 10) + x;
#pragma unroll
                for (int k = 0; k < 16; ++k) {
                    float pooled = fmaxf(B[k], ym[k]);
                    float lm = fmaxf(pooled + thr, 0.f);
                    float sm = 1.f - lm + Dprev[k] + thr;
                    if (st) {
                        out[ob + ((size_t)k << 10)] = lm;
                        out[DOG_ELEMS + ob + ((size_t)k << 10)] = sm;
                    }
                }
            }
#pragma unroll
            for (int k = 0; k < 16; ++k) {
                B[k] = fmaxf(A[k], ym[k]);
                A[k] = ym[k];
                Dprev[k] = gprev[k + 1];             // dog center rows
            }
        }
#pragma unroll
        for (int k = 0; k < 18; ++k) gprev[k] = acc[k];
    }
    if (jhi == 49) {                                 // tail: j=49 (ym_50 = -inf)
        bool st = xok && lane >= 1 && lane <= 62;
        size_t ob = ((size_t)49 << 20) + ((size_t)y0 << 10) + x;
#pragma unroll
        for (int k = 0; k < 16; ++k) {
            float lm = fmaxf(B[k] + thr, 0.f);
            float sm = 1.f - lm + Dprev[k] + thr;
            if (st) {
                out[ob + ((size_t)k << 10)] = lm;
                out[DOG_ELEMS + ob + ((size_t)k << 10)] = sm;
            }
        }
    }
}

extern "C" void kernel_launch(void* const* d_in, const int* in_sizes, int n_in,
                              void* d_out, int out_size, void* d_ws, size_t ws_size,
                              hipStream_t stream) {
    const float* input  = (const float*)d_in[0];
    const float* weight = (const float*)d_in[1];
    const float* sigmas = (const float*)d_in[2];
    const float* thr    = (const float*)d_in[3];
    float* out = (float*)d_out;

    int S = 103;
    if (n_in > 1 && in_sizes[1] >= NS) {
        int s2 = in_sizes[1] / NS;
        S = (int)(sqrt((double)s2) + 0.5);
    }

    size_t need = (size_t)NS * PLANE * 4 + (size_t)NS * WPSTRIDE * 4 + NS * 4 + 256;
    if (ws_size < need) return;   // insufficient scratch -> visible validation failure

    float* tmpH = (float*)d_ws;                    // 51 planes (214 MB)
    float* wp   = tmpH + (size_t)NS * PLANE;       // 51 * 144 floats
    int*   rarr = (int*)(wp + NS * WPSTRIDE);      // 51 ints

    dog_prep <<<NS, 128, 0, stream>>>(weight, wp, rarr, S);
    dog_hblur<<<dim3(512, NS), 256, 0, stream>>>(input, tmpH, wp, rarr);
    dog_fused<<<dim3(16, 17, 5), 256, 0, stream>>>(tmpH, out, wp, rarr, sigmas, thr);
}